// Round 15
// baseline (202.272 us; speedup 1.0000x reference)
//
#include <hip/hip_runtime.h>

// Siamese GeoCheby, round 17: r16 base (201.2 us, best) + ONE structural
// change: k_red1 folded into k_fc2's staging (cross-kernel-boundary fusion,
// NO fences — r15 showed device-scope fences cost ~144us on 8-XCD L2s).
//  - k_fc2 stages sum(8 r1p slices)+b1+relu directly into LDS (identical
//    ascending-k order -> bit-identical h1). Redundant x8 recompute reads
//    48MB of L3-resident r1p (~1-2us) vs one kernel + one launch gap saved.
//  - h1 buffer eliminated. 5 launches -> 4.

#define NN   268
#define EE   8576
#define NG   192
#define FDIM 4288        // 268*16
#define CONVT 1024       // block size
#define NCAST 536        // cast blocks: 536*1024 = 64nt * 134ch * 64lanes

typedef __bf16 bf16_t;
typedef bf16_t bf16x8 __attribute__((ext_vector_type(8)));
typedef bf16_t bf16x4 __attribute__((ext_vector_type(4)));
typedef float  f32x4  __attribute__((ext_vector_type(4)));

// ---- workspace layout (float offsets), fully de-aliased ----
#define WB_OFF   0                                   // wbf: 1024*4288 bf16 = 2195456 f32
#define FB_OFF   2195456                             // 192*4288 bf16 = 411648 f32
#define R1P_OFF  (FB_OFF + 411648)                   // 8*192*1024 f32
#define R2P_OFF  (R1P_OFF + 1572864)                 // 16*192*512 f32
// end ~ 23 MB

// ---------------------------------------------------------------------------
// K1: heterogeneous: blocks [0,192) = fused conv pipeline; blocks
// [192, 192+536) = fc1_w -> wbf fragment cast. (r14/r16 code, unchanged)
// ---------------------------------------------------------------------------
__global__ __launch_bounds__(CONVT) void k_main(
    const float* __restrict__ x0, const float* __restrict__ x1, const float* __restrict__ x2,
    const int* __restrict__ ei0, const int* __restrict__ ei1, const int* __restrict__ ei2,
    const float* __restrict__ ea0, const float* __restrict__ ea1, const float* __restrict__ ea2,
    const float* __restrict__ fc1w, const float* __restrict__ gc1w,
    const float* __restrict__ gc1b, const float* __restrict__ gc4w,
    const float* __restrict__ gc4b, bf16_t* __restrict__ wbf, bf16_t* __restrict__ fout)
{
    __shared__ unsigned int e_s[EE];               // 34.3 KB packed edges
    __shared__ __align__(16) bf16_t A_s[FDIM];     // 8.6 KB (xw1, then H1)
    __shared__ __align__(16) bf16_t S_s[FDIM];     // 8.6 KB (h)
    __shared__ __align__(16) float  xw0_s[FDIM];   // 17.2 KB (x@w0, f32)
    __shared__ __align__(16) bf16_t wxt_s[9216];   // 18 KB [w0|w1] B-fragments
    __shared__ float degS[NN];
    __shared__ int   cntS[NN];
    __shared__ int   offS[NN + 1];
    __shared__ int   curS[NN];
    __shared__ float w4_s[512];
    __shared__ float b1_s[16];
    __shared__ float b4_s[16];
    const int tid = threadIdx.x;

    if (blockIdx.x >= NG) {
        // ---- cast blocks: fc1_w -> wbf in MFMA fragment layout ----
        const int t = (blockIdx.x - NG) * CONVT + tid;
        const int lane = t & 63;
        const int rest = t >> 6;                        // nt*134 + ch
        const int n = (rest / 134) * 16 + (lane & 15);
        const int k = (rest % 134) * 32 + (lane >> 4) * 8;
        const float4 a = *(const float4*)(fc1w + (size_t)n * FDIM + k);
        const float4 b = *(const float4*)(fc1w + (size_t)n * FDIM + k + 4);
        bf16x8 v;
        v[0] = (bf16_t)a.x; v[1] = (bf16_t)a.y; v[2] = (bf16_t)a.z; v[3] = (bf16_t)a.w;
        v[4] = (bf16_t)b.x; v[5] = (bf16_t)b.y; v[6] = (bf16_t)b.z; v[7] = (bf16_t)b.w;
        *(bf16x8*)(wbf + (size_t)t * 8) = v;
        return;
    }

    const int g = blockIdx.x;
    const int br = g >> 6, b = g & 63;
    const float* xg = ((br == 0) ? x0 : (br == 1) ? x1 : x2) + (size_t)b * (NN * NN);
    const int*   ei = (br == 0) ? ei0 : (br == 1) ? ei1 : ei2;
    const float* ea = (br == 0) ? ea0 : (br == 1) ? ea1 : ea2;
    const int*   rowp = ei + (size_t)b * (2 * EE);
    const int*   colp = rowp + EE;
    const float* eap  = ea + (size_t)b * EE;
    const int lane = tid & 63, wid = tid >> 6;

    // ---- self-build wxt B-fragments in LDS (gc1w is 34KB, L2-hot) ----
    for (int idx = tid; idx < 2 * 9 * 64; idx += CONVT) {
        const int l = idx & 63, chunk = (idx >> 6) % 9, nt = idx / (9 * 64);
        const int n = l & 15, q = l >> 4;
        bf16x8 v;
#pragma unroll
        for (int j = 0; j < 8; ++j) {
            const int k = chunk * 32 + q * 8 + j;
            v[j] = (k < NN) ? (bf16_t)gc1w[nt * FDIM + k * 16 + n] : (bf16_t)0.f;
        }
        *(bf16x8*)&wxt_s[(size_t)idx * 8] = v;
    }
    if (tid < NN) { degS[tid] = 0.f; cntS[tid] = 0; }
    if (tid < 512) w4_s[tid] = gc4w[tid];
    if (tid < 16) { b1_s[tid] = gc1b[tid]; b4_s[tid] = gc4b[tid]; }
    __syncthreads();   // wxt_s ready

    // ---- fused xw = x @ [w0|w1] via MFMA, straight into LDS ----
    {
        const int q = lane >> 4, nlo = lane & 15;
        for (int mt = wid; mt < 17; mt += 16) {
            const int mrow = mt * 16 + nlo;
            const bool mvalid = (mrow < NN);
            const float* xrow = xg + (size_t)mrow * NN;
            f32x4 acc0 = {0.f, 0.f, 0.f, 0.f}, acc1 = {0.f, 0.f, 0.f, 0.f};
            for (int ch = 0; ch < 9; ++ch) {
                const int k0 = ch * 32 + q * 8;
                float4 p0 = make_float4(0.f, 0.f, 0.f, 0.f);
                float4 p1 = make_float4(0.f, 0.f, 0.f, 0.f);
                if (mvalid) {
                    if (k0 < NN)     p0 = *(const float4*)(xrow + k0);
                    if (k0 + 4 < NN) p1 = *(const float4*)(xrow + k0 + 4);
                }
                bf16x8 a;
                a[0] = (bf16_t)p0.x; a[1] = (bf16_t)p0.y; a[2] = (bf16_t)p0.z; a[3] = (bf16_t)p0.w;
                a[4] = (bf16_t)p1.x; a[5] = (bf16_t)p1.y; a[6] = (bf16_t)p1.z; a[7] = (bf16_t)p1.w;
                const bf16x8 b0 = *(const bf16x8*)&wxt_s[(size_t)(ch * 64 + lane) * 8];
                const bf16x8 b1 = *(const bf16x8*)&wxt_s[(size_t)(576 + ch * 64 + lane) * 8];
                acc0 = __builtin_amdgcn_mfma_f32_16x16x32_bf16(a, b0, acc0, 0, 0, 0);
                acc1 = __builtin_amdgcn_mfma_f32_16x16x32_bf16(a, b1, acc1, 0, 0, 0);
            }
#pragma unroll
            for (int r = 0; r < 4; ++r) {
                const int row = mt * 16 + q * 4 + r;
                if (row < NN) {
                    xw0_s[row * 16 + nlo] = acc0[r];
                    A_s[row * 16 + nlo] = (bf16_t)acc1[r];
                }
            }
        }
    }
    __syncthreads();

    // pass 1: degree + count
    for (int e = tid; e < EE; e += CONVT) {
        const int r = rowp[e];
        atomicAdd(&degS[r], eap[e]);
        atomicAdd(&cntS[r], 1);
    }
    // inclusive Hillis-Steele scan of cntS
    for (int st = 1; st < NN; st <<= 1) {
        __syncthreads();
        int v = 0;
        if (tid < NN) { v = cntS[tid]; if (tid >= st) v += cntS[tid - st]; }
        __syncthreads();
        if (tid < NN) cntS[tid] = v;
    }
    __syncthreads();
    if (tid < NN) offS[tid + 1] = cntS[tid];
    if (tid == 0) offS[0] = 0;
    __syncthreads();
    if (tid < NN) {
        curS[tid] = offS[tid];
        const float d = degS[tid];
        degS[tid] = (d > 0.f) ? rsqrtf(d) : 0.f;   // degS becomes dis
    }
    __syncthreads();
    // pass 2: scatter packed edges into LDS CSR
    for (int e = tid; e < EE; e += CONVT) {
        const int r = rowp[e], c = colp[e];
        const float nv = -eap[e] * degS[r] * degS[c];
        union { float f; unsigned u; } cv; cv.f = nv;
        const unsigned bits = (cv.u + 0x7fffu + ((cv.u >> 16) & 1u)) >> 16;   // RNE to bf16
        const int pos = atomicAdd(&curS[r], 1);
        e_s[pos] = ((unsigned)c << 16) | bits;
    }
    __syncthreads();

    const int j4 = tid & 3, nl = tid >> 2;         // nl in 0..255
    const bf16x4* A4 = (const bf16x4*)A_s;

    // conv1: h = relu(xw0_s + gather(A_s) + b1) -> S_s (bf16)
    for (int n = nl; n < NN; n += 256) {
        const int s = offS[n], e = offS[n + 1];
        const f32x4 xv = *(const f32x4*)&xw0_s[n * 16 + j4 * 4];
        float ax = 0.f, ay = 0.f, az = 0.f, aw = 0.f;
        int i = s;
        for (; i + 3 < e; i += 4) {
            const unsigned p0 = e_s[i], p1 = e_s[i + 1], p2 = e_s[i + 2], p3 = e_s[i + 3];
            const float w0 = __uint_as_float(p0 << 16);
            const float w1 = __uint_as_float(p1 << 16);
            const float w2 = __uint_as_float(p2 << 16);
            const float w3 = __uint_as_float(p3 << 16);
            const bf16x4 a0 = A4[(p0 >> 16) * 4 + j4];
            const bf16x4 a1 = A4[(p1 >> 16) * 4 + j4];
            const bf16x4 a2 = A4[(p2 >> 16) * 4 + j4];
            const bf16x4 a3 = A4[(p3 >> 16) * 4 + j4];
            ax += w0 * (float)a0[0] + w1 * (float)a1[0] + w2 * (float)a2[0] + w3 * (float)a3[0];
            ay += w0 * (float)a0[1] + w1 * (float)a1[1] + w2 * (float)a2[1] + w3 * (float)a3[1];
            az += w0 * (float)a0[2] + w1 * (float)a1[2] + w2 * (float)a2[2] + w3 * (float)a3[2];
            aw += w0 * (float)a0[3] + w1 * (float)a1[3] + w2 * (float)a2[3] + w3 * (float)a3[3];
        }
        for (; i < e; ++i) {
            const unsigned p0 = e_s[i];
            const float w0 = __uint_as_float(p0 << 16);
            const bf16x4 a0 = A4[(p0 >> 16) * 4 + j4];
            ax += w0 * (float)a0[0]; ay += w0 * (float)a0[1];
            az += w0 * (float)a0[2]; aw += w0 * (float)a0[3];
        }
        bf16x4 h;
        h[0] = (bf16_t)fmaxf(xv[0] + ax + b1_s[j4 * 4 + 0], 0.f);
        h[1] = (bf16_t)fmaxf(xv[1] + ay + b1_s[j4 * 4 + 1], 0.f);
        h[2] = (bf16_t)fmaxf(xv[2] + az + b1_s[j4 * 4 + 2], 0.f);
        h[3] = (bf16_t)fmaxf(xv[3] + aw + b1_s[j4 * 4 + 3], 0.f);
        *(bf16x4*)&S_s[n * 16 + j4 * 4] = h;
    }
    __syncthreads();

    // H1 = h @ w4[1] -> A_s (vectorized S_s row reads)
    for (int idx = tid; idx < FDIM; idx += CONVT) {
        const int n = idx >> 4, j = idx & 15;
        const bf16x8 s0 = *(const bf16x8*)&S_s[n * 16];
        const bf16x8 s1 = *(const bf16x8*)&S_s[n * 16 + 8];
        float a1 = 0.f;
#pragma unroll
        for (int k = 0; k < 8; ++k) a1 += (float)s0[k] * w4_s[256 + k * 16 + j];
#pragma unroll
        for (int k = 0; k < 8; ++k) a1 += (float)s1[k] * w4_s[256 + (k + 8) * 16 + j];
        A_s[idx] = (bf16_t)a1;
    }
    __syncthreads();

    // conv2: f = h @ w4[0] + b4 + gather(H1)  -> fout (bf16)
    for (int n = nl; n < NN; n += 256) {
        const int s = offS[n], e = offS[n + 1];
        float ax = 0.f, ay = 0.f, az = 0.f, aw = 0.f;
        int i = s;
        for (; i + 3 < e; i += 4) {
            const unsigned p0 = e_s[i], p1 = e_s[i + 1], p2 = e_s[i + 2], p3 = e_s[i + 3];
            const float w0 = __uint_as_float(p0 << 16);
            const float w1 = __uint_as_float(p1 << 16);
            const float w2 = __uint_as_float(p2 << 16);
            const float w3 = __uint_as_float(p3 << 16);
            const bf16x4 a0 = A4[(p0 >> 16) * 4 + j4];
            const bf16x4 a1 = A4[(p1 >> 16) * 4 + j4];
            const bf16x4 a2 = A4[(p2 >> 16) * 4 + j4];
            const bf16x4 a3 = A4[(p3 >> 16) * 4 + j4];
            ax += w0 * (float)a0[0] + w1 * (float)a1[0] + w2 * (float)a2[0] + w3 * (float)a3[0];
            ay += w0 * (float)a0[1] + w1 * (float)a1[1] + w2 * (float)a2[1] + w3 * (float)a3[1];
            az += w0 * (float)a0[2] + w1 * (float)a1[2] + w2 * (float)a2[2] + w3 * (float)a3[2];
            aw += w0 * (float)a0[3] + w1 * (float)a1[3] + w2 * (float)a2[3] + w3 * (float)a3[3];
        }
        for (; i < e; ++i) {
            const unsigned p0 = e_s[i];
            const float w0 = __uint_as_float(p0 << 16);
            const bf16x4 a0 = A4[(p0 >> 16) * 4 + j4];
            ax += w0 * (float)a0[0]; ay += w0 * (float)a0[1];
            az += w0 * (float)a0[2]; aw += w0 * (float)a0[3];
        }
        float h0[4];
#pragma unroll
        for (int c2 = 0; c2 < 4; ++c2) h0[c2] = b4_s[j4 * 4 + c2];
        const bf16x8 s0 = *(const bf16x8*)&S_s[n * 16];
        const bf16x8 s1 = *(const bf16x8*)&S_s[n * 16 + 8];
#pragma unroll
        for (int k = 0; k < 8; ++k) {
            const float sv = (float)s0[k];
#pragma unroll
            for (int c2 = 0; c2 < 4; ++c2) h0[c2] += sv * w4_s[k * 16 + j4 * 4 + c2];
        }
#pragma unroll
        for (int k = 0; k < 8; ++k) {
            const float sv = (float)s1[k];
#pragma unroll
            for (int c2 = 0; c2 < 4; ++c2) h0[c2] += sv * w4_s[(k + 8) * 16 + j4 * 4 + c2];
        }
        bf16x4 o;
        o[0] = (bf16_t)(h0[0] + ax); o[1] = (bf16_t)(h0[1] + ay);
        o[2] = (bf16_t)(h0[2] + az); o[3] = (bf16_t)(h0[3] + aw);
        *(bf16x4*)(fout + (size_t)g * FDIM + n * 16 + j4 * 4) = o;
    }
}

// ---------------------------------------------------------------------------
// K3: fc1 MFMA (fragment-layout B), XCD-swizzled: XCD x runs kz-slice x.
// ---------------------------------------------------------------------------
__global__ __launch_bounds__(256) void k_fc1(
    const bf16_t* __restrict__ fb, const bf16_t* __restrict__ wbf, float* __restrict__ r1p)
{
    const int bid = blockIdx.x;                      // [0,768)
    const int cid = (bid & 7) * 96 + (bid >> 3);     // XCD-contiguous remap
    const int mt = cid % 12, nb = (cid / 12) & 7, kz = cid / 96;
    const int wid = threadIdx.x >> 6, lane = threadIdx.x & 63;
    const int q = lane >> 4, nlo = lane & 15;
    const int n0 = nb * 128 + wid * 32;
    const int cstart = kz * 17;                    // 134 chunks: 7*17 + 15
    const int ccnt   = (kz == 7) ? 15 : 17;

    const bf16_t* arow = fb + (size_t)(mt * 16 + nlo) * FDIM + q * 8;
    const int nt0 = nb * 8 + wid * 2;              // 16-col tile index for t=0
    f32x4 acc[2];
#pragma unroll
    for (int t = 0; t < 2; ++t) { acc[t][0]=0.f; acc[t][1]=0.f; acc[t][2]=0.f; acc[t][3]=0.f; }

    for (int ch = 0; ch < ccnt; ++ch) {
        const size_t ko = (size_t)(cstart + ch) * 32;
        const bf16x8 a = *(const bf16x8*)(arow + ko);
#pragma unroll
        for (int t = 0; t < 2; ++t) {
            const bf16x8 bv = *(const bf16x8*)(
                wbf + (((size_t)(nt0 + t) * 134 + cstart + ch) * 64 + lane) * 8);
            acc[t] = __builtin_amdgcn_mfma_f32_16x16x32_bf16(a, bv, acc[t], 0, 0, 0);
        }
    }
    float* outp = r1p + (size_t)kz * (NG * 1024);
#pragma unroll
    for (int t = 0; t < 2; ++t)
#pragma unroll
        for (int r = 0; r < 4; ++r)
            outp[(size_t)(mt * 16 + q * 4 + r) * 1024 + n0 + t * 16 + nlo] = acc[t][r];
}

// ---------------------------------------------------------------------------
// K5: fc2 partials, with k_red1 FOLDED into staging: rs tile = relu(sum of
// 8 r1p slices + b1). XCD-swizzled. 384 blocks.
// ---------------------------------------------------------------------------
__global__ __launch_bounds__(256) void k_fc2(
    const float* __restrict__ r1p, const float* __restrict__ w2,
    const float* __restrict__ b1, float* __restrict__ r2p)
{
    const int bid = blockIdx.x;                      // [0,384)
    const int cid = (bid & 7) * 48 + (bid >> 3);     // XCD-contiguous remap
    const int bx = cid % 3, by = (cid / 3) & 7, bz = cid / 24;
    const int m0 = bx * 64;
    const int n0 = by * 64;
    const int kb = bz * 64;
    __shared__ float rs[64][68];
    __shared__ float wss[64][68];
    const int tid = threadIdx.x;
    const int mt = tid & 15, nt = tid >> 4;
    float acc[4][4];
#pragma unroll
    for (int i = 0; i < 4; ++i)
#pragma unroll
        for (int j = 0; j < 4; ++j) acc[i][j] = 0.f;

    const size_t S = (size_t)NG * 1024;
    for (int idx = tid; idx < 1024; idx += 256) {
        const int r = idx >> 4, qq = idx & 15;
        const int gk = kb + qq * 4;
        // rs = h1 tile computed inline: relu(sum_kz r1p + b1)  (k_red1 order)
        const size_t hidx = (size_t)(m0 + r) * 1024 + gk;
        float4 s = *(const float4*)(r1p + hidx);
#pragma unroll
        for (int k = 1; k < 8; ++k) {
            const float4 t = *(const float4*)(r1p + (size_t)k * S + hidx);
            s.x += t.x; s.y += t.y; s.z += t.z; s.w += t.w;
        }
        const float4 bb = *(const float4*)(b1 + gk);
        float4 o;
        o.x = fmaxf(s.x + bb.x, 0.f);
        o.y = fmaxf(s.y + bb.y, 0.f);
        o.z = fmaxf(s.z + bb.z, 0.f);
        o.w = fmaxf(s.w + bb.w, 0.f);
        *(float4*)&rs[r][qq * 4] = o;
        *(float4*)&wss[r][qq * 4] = *(const float4*)(w2 + (size_t)(n0 + r) * 1024 + gk);
    }
    __syncthreads();
    for (int kq = 0; kq < 16; ++kq) {
        float4 av[4], bv[4];
#pragma unroll
        for (int i = 0; i < 4; ++i) av[i] = *(const float4*)&rs[mt + 16 * i][kq * 4];
#pragma unroll
        for (int j = 0; j < 4; ++j) bv[j] = *(const float4*)&wss[nt + 16 * j][kq * 4];
#pragma unroll
        for (int i = 0; i < 4; ++i)
#pragma unroll
            for (int j = 0; j < 4; ++j)
                acc[i][j] += av[i].x * bv[j].x + av[i].y * bv[j].y +
                             av[i].z * bv[j].z + av[i].w * bv[j].w;
    }
    float* outp = r2p + (size_t)bz * (NG * 512);
#pragma unroll
    for (int i = 0; i < 4; ++i)
#pragma unroll
        for (int j = 0; j < 4; ++j)
            outp[(size_t)(m0 + mt + 16 * i) * 512 + n0 + nt + 16 * j] = acc[i][j];
}

// K6: out = sum_kz r2p + fc2_b, 16 slices
__global__ __launch_bounds__(256) void k_red2(
    const float* __restrict__ r2p, const float* __restrict__ b2, float* __restrict__ out)
{
    const size_t i = ((size_t)blockIdx.x * 256 + threadIdx.x) * 4;
    const size_t S = (size_t)NG * 512;
    float4 s = *(const float4*)(r2p + i);
#pragma unroll
    for (int k = 1; k < 16; ++k) {
        const float4 t = *(const float4*)(r2p + (size_t)k * S + i);
        s.x += t.x; s.y += t.y; s.z += t.z; s.w += t.w;
    }
    const float4 bb = *(const float4*)(b2 + (i & 511));
    s.x += bb.x; s.y += bb.y; s.z += bb.z; s.w += bb.w;
    *(float4*)(out + i) = s;
}

// ---------------------------------------------------------------------------
extern "C" void kernel_launch(void* const* d_in, const int* in_sizes, int n_in,
                              void* d_out, int out_size, void* d_ws, size_t ws_size,
                              hipStream_t stream)
{
    const float* x0   = (const float*)d_in[0];
    const float* x1   = (const float*)d_in[1];
    const float* x2   = (const float*)d_in[2];
    const int*   ei0  = (const int*)d_in[3];
    const int*   ei1  = (const int*)d_in[4];
    const int*   ei2  = (const int*)d_in[5];
    const float* ea0  = (const float*)d_in[6];
    const float* ea1  = (const float*)d_in[7];
    const float* ea2  = (const float*)d_in[8];
    const float* gc1w = (const float*)d_in[9];
    const float* gc1b = (const float*)d_in[10];
    const float* gc4w = (const float*)d_in[11];
    const float* gc4b = (const float*)d_in[12];
    const float* fc1w = (const float*)d_in[13];
    const float* fc1b = (const float*)d_in[14];
    const float* fc2w = (const float*)d_in[15];
    const float* fc2b = (const float*)d_in[16];

    float*  ws  = (float*)d_ws;
    bf16_t* wbf = (bf16_t*)(ws + WB_OFF);
    bf16_t* fb  = (bf16_t*)(ws + FB_OFF);
    float*  r1p = ws + R1P_OFF;
    float*  r2p = ws + R2P_OFF;
    float*  out = (float*)d_out;

    k_main<<<NG + NCAST, CONVT, 0, stream>>>(x0, x1, x2, ei0, ei1, ei2,
                                             ea0, ea1, ea2, fc1w, gc1w,
                                             gc1b, gc4w, gc4b, wbf, fb);
    k_fc1 <<<768, 256, 0, stream>>>(fb, wbf, r1p);
    k_fc2 <<<384, 256, 0, stream>>>(r1p, fc2w, fc1b, r2p);
    k_red2<<<96, 256, 0, stream>>>(r2p, fc2b, out);
}

// Round 16
// 199.782 us; speedup vs baseline: 1.0125x; 1.0125x over previous
//
#include <hip/hip_runtime.h>

// Siamese GeoCheby, round 18: r17 base (202.3us, ~= best 201.2 within noise,
// 4 launches) + ONE change: k_fc1's A-fragment loads staged through LDS.
//  - was: per-lane 16B A-loads at 8576B lane stride = 64 scattered
//    transactions per bf16x8 (same pathology fixed for B in r12, +8.4us).
//  - now: block stages its 16 A-rows x kz-slice (<=1088B/row, contiguous)
//    into LDS with coalesced float4 loads; rows padded to 1092B (odd dword
//    stride -> conflict-free ds_read_b128); fragments read from LDS.
//  Everything else byte-identical to r17.

#define NN   268
#define EE   8576
#define NG   192
#define FDIM 4288        // 268*16
#define CONVT 1024       // block size
#define NCAST 536        // cast blocks: 536*1024 = 64nt * 134ch * 64lanes

typedef __bf16 bf16_t;
typedef bf16_t bf16x8 __attribute__((ext_vector_type(8)));
typedef bf16_t bf16x4 __attribute__((ext_vector_type(4)));
typedef float  f32x4  __attribute__((ext_vector_type(4)));

// ---- workspace layout (float offsets), fully de-aliased ----
#define WB_OFF   0                                   // wbf: 1024*4288 bf16 = 2195456 f32
#define FB_OFF   2195456                             // 192*4288 bf16 = 411648 f32
#define R1P_OFF  (FB_OFF + 411648)                   // 8*192*1024 f32
#define R2P_OFF  (R1P_OFF + 1572864)                 // 16*192*512 f32
// end ~ 23 MB

// ---------------------------------------------------------------------------
// K1: heterogeneous: blocks [0,192) = fused conv pipeline; blocks
// [192, 192+536) = fc1_w -> wbf fragment cast. (unchanged)
// ---------------------------------------------------------------------------
__global__ __launch_bounds__(CONVT) void k_main(
    const float* __restrict__ x0, const float* __restrict__ x1, const float* __restrict__ x2,
    const int* __restrict__ ei0, const int* __restrict__ ei1, const int* __restrict__ ei2,
    const float* __restrict__ ea0, const float* __restrict__ ea1, const float* __restrict__ ea2,
    const float* __restrict__ fc1w, const float* __restrict__ gc1w,
    const float* __restrict__ gc1b, const float* __restrict__ gc4w,
    const float* __restrict__ gc4b, bf16_t* __restrict__ wbf, bf16_t* __restrict__ fout)
{
    __shared__ unsigned int e_s[EE];               // 34.3 KB packed edges
    __shared__ __align__(16) bf16_t A_s[FDIM];     // 8.6 KB (xw1, then H1)
    __shared__ __align__(16) bf16_t S_s[FDIM];     // 8.6 KB (h)
    __shared__ __align__(16) float  xw0_s[FDIM];   // 17.2 KB (x@w0, f32)
    __shared__ __align__(16) bf16_t wxt_s[9216];   // 18 KB [w0|w1] B-fragments
    __shared__ float degS[NN];
    __shared__ int   cntS[NN];
    __shared__ int   offS[NN + 1];
    __shared__ int   curS[NN];
    __shared__ float w4_s[512];
    __shared__ float b1_s[16];
    __shared__ float b4_s[16];
    const int tid = threadIdx.x;

    if (blockIdx.x >= NG) {
        // ---- cast blocks: fc1_w -> wbf in MFMA fragment layout ----
        const int t = (blockIdx.x - NG) * CONVT + tid;
        const int lane = t & 63;
        const int rest = t >> 6;                        // nt*134 + ch
        const int n = (rest / 134) * 16 + (lane & 15);
        const int k = (rest % 134) * 32 + (lane >> 4) * 8;
        const float4 a = *(const float4*)(fc1w + (size_t)n * FDIM + k);
        const float4 b = *(const float4*)(fc1w + (size_t)n * FDIM + k + 4);
        bf16x8 v;
        v[0] = (bf16_t)a.x; v[1] = (bf16_t)a.y; v[2] = (bf16_t)a.z; v[3] = (bf16_t)a.w;
        v[4] = (bf16_t)b.x; v[5] = (bf16_t)b.y; v[6] = (bf16_t)b.z; v[7] = (bf16_t)b.w;
        *(bf16x8*)(wbf + (size_t)t * 8) = v;
        return;
    }

    const int g = blockIdx.x;
    const int br = g >> 6, b = g & 63;
    const float* xg = ((br == 0) ? x0 : (br == 1) ? x1 : x2) + (size_t)b * (NN * NN);
    const int*   ei = (br == 0) ? ei0 : (br == 1) ? ei1 : ei2;
    const float* ea = (br == 0) ? ea0 : (br == 1) ? ea1 : ea2;
    const int*   rowp = ei + (size_t)b * (2 * EE);
    const int*   colp = rowp + EE;
    const float* eap  = ea + (size_t)b * EE;
    const int lane = tid & 63, wid = tid >> 6;

    // ---- self-build wxt B-fragments in LDS (gc1w is 34KB, L2-hot) ----
    for (int idx = tid; idx < 2 * 9 * 64; idx += CONVT) {
        const int l = idx & 63, chunk = (idx >> 6) % 9, nt = idx / (9 * 64);
        const int n = l & 15, q = l >> 4;
        bf16x8 v;
#pragma unroll
        for (int j = 0; j < 8; ++j) {
            const int k = chunk * 32 + q * 8 + j;
            v[j] = (k < NN) ? (bf16_t)gc1w[nt * FDIM + k * 16 + n] : (bf16_t)0.f;
        }
        *(bf16x8*)&wxt_s[(size_t)idx * 8] = v;
    }
    if (tid < NN) { degS[tid] = 0.f; cntS[tid] = 0; }
    if (tid < 512) w4_s[tid] = gc4w[tid];
    if (tid < 16) { b1_s[tid] = gc1b[tid]; b4_s[tid] = gc4b[tid]; }
    __syncthreads();   // wxt_s ready

    // ---- fused xw = x @ [w0|w1] via MFMA, straight into LDS ----
    {
        const int q = lane >> 4, nlo = lane & 15;
        for (int mt = wid; mt < 17; mt += 16) {
            const int mrow = mt * 16 + nlo;
            const bool mvalid = (mrow < NN);
            const float* xrow = xg + (size_t)mrow * NN;
            f32x4 acc0 = {0.f, 0.f, 0.f, 0.f}, acc1 = {0.f, 0.f, 0.f, 0.f};
            for (int ch = 0; ch < 9; ++ch) {
                const int k0 = ch * 32 + q * 8;
                float4 p0 = make_float4(0.f, 0.f, 0.f, 0.f);
                float4 p1 = make_float4(0.f, 0.f, 0.f, 0.f);
                if (mvalid) {
                    if (k0 < NN)     p0 = *(const float4*)(xrow + k0);
                    if (k0 + 4 < NN) p1 = *(const float4*)(xrow + k0 + 4);
                }
                bf16x8 a;
                a[0] = (bf16_t)p0.x; a[1] = (bf16_t)p0.y; a[2] = (bf16_t)p0.z; a[3] = (bf16_t)p0.w;
                a[4] = (bf16_t)p1.x; a[5] = (bf16_t)p1.y; a[6] = (bf16_t)p1.z; a[7] = (bf16_t)p1.w;
                const bf16x8 b0 = *(const bf16x8*)&wxt_s[(size_t)(ch * 64 + lane) * 8];
                const bf16x8 b1 = *(const bf16x8*)&wxt_s[(size_t)(576 + ch * 64 + lane) * 8];
                acc0 = __builtin_amdgcn_mfma_f32_16x16x32_bf16(a, b0, acc0, 0, 0, 0);
                acc1 = __builtin_amdgcn_mfma_f32_16x16x32_bf16(a, b1, acc1, 0, 0, 0);
            }
#pragma unroll
            for (int r = 0; r < 4; ++r) {
                const int row = mt * 16 + q * 4 + r;
                if (row < NN) {
                    xw0_s[row * 16 + nlo] = acc0[r];
                    A_s[row * 16 + nlo] = (bf16_t)acc1[r];
                }
            }
        }
    }
    __syncthreads();

    // pass 1: degree + count
    for (int e = tid; e < EE; e += CONVT) {
        const int r = rowp[e];
        atomicAdd(&degS[r], eap[e]);
        atomicAdd(&cntS[r], 1);
    }
    // inclusive Hillis-Steele scan of cntS
    for (int st = 1; st < NN; st <<= 1) {
        __syncthreads();
        int v = 0;
        if (tid < NN) { v = cntS[tid]; if (tid >= st) v += cntS[tid - st]; }
        __syncthreads();
        if (tid < NN) cntS[tid] = v;
    }
    __syncthreads();
    if (tid < NN) offS[tid + 1] = cntS[tid];
    if (tid == 0) offS[0] = 0;
    __syncthreads();
    if (tid < NN) {
        curS[tid] = offS[tid];
        const float d = degS[tid];
        degS[tid] = (d > 0.f) ? rsqrtf(d) : 0.f;   // degS becomes dis
    }
    __syncthreads();
    // pass 2: scatter packed edges into LDS CSR
    for (int e = tid; e < EE; e += CONVT) {
        const int r = rowp[e], c = colp[e];
        const float nv = -eap[e] * degS[r] * degS[c];
        union { float f; unsigned u; } cv; cv.f = nv;
        const unsigned bits = (cv.u + 0x7fffu + ((cv.u >> 16) & 1u)) >> 16;   // RNE to bf16
        const int pos = atomicAdd(&curS[r], 1);
        e_s[pos] = ((unsigned)c << 16) | bits;
    }
    __syncthreads();

    const int j4 = tid & 3, nl = tid >> 2;         // nl in 0..255
    const bf16x4* A4 = (const bf16x4*)A_s;

    // conv1: h = relu(xw0_s + gather(A_s) + b1) -> S_s (bf16)
    for (int n = nl; n < NN; n += 256) {
        const int s = offS[n], e = offS[n + 1];
        const f32x4 xv = *(const f32x4*)&xw0_s[n * 16 + j4 * 4];
        float ax = 0.f, ay = 0.f, az = 0.f, aw = 0.f;
        int i = s;
        for (; i + 3 < e; i += 4) {
            const unsigned p0 = e_s[i], p1 = e_s[i + 1], p2 = e_s[i + 2], p3 = e_s[i + 3];
            const float w0 = __uint_as_float(p0 << 16);
            const float w1 = __uint_as_float(p1 << 16);
            const float w2 = __uint_as_float(p2 << 16);
            const float w3 = __uint_as_float(p3 << 16);
            const bf16x4 a0 = A4[(p0 >> 16) * 4 + j4];
            const bf16x4 a1 = A4[(p1 >> 16) * 4 + j4];
            const bf16x4 a2 = A4[(p2 >> 16) * 4 + j4];
            const bf16x4 a3 = A4[(p3 >> 16) * 4 + j4];
            ax += w0 * (float)a0[0] + w1 * (float)a1[0] + w2 * (float)a2[0] + w3 * (float)a3[0];
            ay += w0 * (float)a0[1] + w1 * (float)a1[1] + w2 * (float)a2[1] + w3 * (float)a3[1];
            az += w0 * (float)a0[2] + w1 * (float)a1[2] + w2 * (float)a2[2] + w3 * (float)a3[2];
            aw += w0 * (float)a0[3] + w1 * (float)a1[3] + w2 * (float)a2[3] + w3 * (float)a3[3];
        }
        for (; i < e; ++i) {
            const unsigned p0 = e_s[i];
            const float w0 = __uint_as_float(p0 << 16);
            const bf16x4 a0 = A4[(p0 >> 16) * 4 + j4];
            ax += w0 * (float)a0[0]; ay += w0 * (float)a0[1];
            az += w0 * (float)a0[2]; aw += w0 * (float)a0[3];
        }
        bf16x4 h;
        h[0] = (bf16_t)fmaxf(xv[0] + ax + b1_s[j4 * 4 + 0], 0.f);
        h[1] = (bf16_t)fmaxf(xv[1] + ay + b1_s[j4 * 4 + 1], 0.f);
        h[2] = (bf16_t)fmaxf(xv[2] + az + b1_s[j4 * 4 + 2], 0.f);
        h[3] = (bf16_t)fmaxf(xv[3] + aw + b1_s[j4 * 4 + 3], 0.f);
        *(bf16x4*)&S_s[n * 16 + j4 * 4] = h;
    }
    __syncthreads();

    // H1 = h @ w4[1] -> A_s (vectorized S_s row reads)
    for (int idx = tid; idx < FDIM; idx += CONVT) {
        const int n = idx >> 4, j = idx & 15;
        const bf16x8 s0 = *(const bf16x8*)&S_s[n * 16];
        const bf16x8 s1 = *(const bf16x8*)&S_s[n * 16 + 8];
        float a1 = 0.f;
#pragma unroll
        for (int k = 0; k < 8; ++k) a1 += (float)s0[k] * w4_s[256 + k * 16 + j];
#pragma unroll
        for (int k = 0; k < 8; ++k) a1 += (float)s1[k] * w4_s[256 + (k + 8) * 16 + j];
        A_s[idx] = (bf16_t)a1;
    }
    __syncthreads();

    // conv2: f = h @ w4[0] + b4 + gather(H1)  -> fout (bf16)
    for (int n = nl; n < NN; n += 256) {
        const int s = offS[n], e = offS[n + 1];
        float ax = 0.f, ay = 0.f, az = 0.f, aw = 0.f;
        int i = s;
        for (; i + 3 < e; i += 4) {
            const unsigned p0 = e_s[i], p1 = e_s[i + 1], p2 = e_s[i + 2], p3 = e_s[i + 3];
            const float w0 = __uint_as_float(p0 << 16);
            const float w1 = __uint_as_float(p1 << 16);
            const float w2 = __uint_as_float(p2 << 16);
            const float w3 = __uint_as_float(p3 << 16);
            const bf16x4 a0 = A4[(p0 >> 16) * 4 + j4];
            const bf16x4 a1 = A4[(p1 >> 16) * 4 + j4];
            const bf16x4 a2 = A4[(p2 >> 16) * 4 + j4];
            const bf16x4 a3 = A4[(p3 >> 16) * 4 + j4];
            ax += w0 * (float)a0[0] + w1 * (float)a1[0] + w2 * (float)a2[0] + w3 * (float)a3[0];
            ay += w0 * (float)a0[1] + w1 * (float)a1[1] + w2 * (float)a2[1] + w3 * (float)a3[1];
            az += w0 * (float)a0[2] + w1 * (float)a1[2] + w2 * (float)a2[2] + w3 * (float)a3[2];
            aw += w0 * (float)a0[3] + w1 * (float)a1[3] + w2 * (float)a2[3] + w3 * (float)a3[3];
        }
        for (; i < e; ++i) {
            const unsigned p0 = e_s[i];
            const float w0 = __uint_as_float(p0 << 16);
            const bf16x4 a0 = A4[(p0 >> 16) * 4 + j4];
            ax += w0 * (float)a0[0]; ay += w0 * (float)a0[1];
            az += w0 * (float)a0[2]; aw += w0 * (float)a0[3];
        }
        float h0[4];
#pragma unroll
        for (int c2 = 0; c2 < 4; ++c2) h0[c2] = b4_s[j4 * 4 + c2];
        const bf16x8 s0 = *(const bf16x8*)&S_s[n * 16];
        const bf16x8 s1 = *(const bf16x8*)&S_s[n * 16 + 8];
#pragma unroll
        for (int k = 0; k < 8; ++k) {
            const float sv = (float)s0[k];
#pragma unroll
            for (int c2 = 0; c2 < 4; ++c2) h0[c2] += sv * w4_s[k * 16 + j4 * 4 + c2];
        }
#pragma unroll
        for (int k = 0; k < 8; ++k) {
            const float sv = (float)s1[k];
#pragma unroll
            for (int c2 = 0; c2 < 4; ++c2) h0[c2] += sv * w4_s[(k + 8) * 16 + j4 * 4 + c2];
        }
        bf16x4 o;
        o[0] = (bf16_t)(h0[0] + ax); o[1] = (bf16_t)(h0[1] + ay);
        o[2] = (bf16_t)(h0[2] + az); o[3] = (bf16_t)(h0[3] + aw);
        *(bf16x4*)(fout + (size_t)g * FDIM + n * 16 + j4 * 4) = o;
    }
}

// ---------------------------------------------------------------------------
// K3: fc1 MFMA (fragment-layout B), XCD-swizzled, A staged via LDS:
// block loads its 16 A-rows x kz-slice (contiguous 1088B/row) coalesced into
// LDS (rows padded to 1092B = 273 dwords, odd -> conflict-free b128 reads).
// ---------------------------------------------------------------------------
__global__ __launch_bounds__(256) void k_fc1(
    const bf16_t* __restrict__ fb, const bf16_t* __restrict__ wbf, float* __restrict__ r1p)
{
    const int bid = blockIdx.x;                      // [0,768)
    const int cid = (bid & 7) * 96 + (bid >> 3);     // XCD-contiguous remap
    const int mt = cid % 12, nb = (cid / 12) & 7, kz = cid / 96;
    const int wid = threadIdx.x >> 6, lane = threadIdx.x & 63;
    const int q = lane >> 4, nlo = lane & 15;
    const int n0 = nb * 128 + wid * 32;
    const int cstart = kz * 17;                    // 134 chunks: 7*17 + 15
    const int ccnt   = (kz == 7) ? 15 : 17;

    __shared__ __align__(16) bf16_t As[16 * 546];  // 546 bf16 = 1092B rows

    // stage: 16 rows x ccnt*32 bf16 (contiguous per row), coalesced float4
    {
        const int tid = threadIdx.x;
        const int nseg = ccnt * 4;                 // 16B segs per row (<=68)
        for (int i = tid; i < 16 * nseg; i += 256) {
            const int r = i / nseg, sgi = i % nseg;
            *(float4*)&As[r * 546 + sgi * 8] =
                *(const float4*)(fb + (size_t)(mt * 16 + r) * FDIM + cstart * 32 + sgi * 8);
        }
    }
    __syncthreads();

    const int nt0 = nb * 8 + wid * 2;              // 16-col tile index for t=0
    f32x4 acc[2];
#pragma unroll
    for (int t = 0; t < 2; ++t) { acc[t][0]=0.f; acc[t][1]=0.f; acc[t][2]=0.f; acc[t][3]=0.f; }

    for (int ch = 0; ch < ccnt; ++ch) {
        const bf16x8 a = *(const bf16x8*)&As[nlo * 546 + ch * 32 + q * 8];
#pragma unroll
        for (int t = 0; t < 2; ++t) {
            const bf16x8 bv = *(const bf16x8*)(
                wbf + (((size_t)(nt0 + t) * 134 + cstart + ch) * 64 + lane) * 8);
            acc[t] = __builtin_amdgcn_mfma_f32_16x16x32_bf16(a, bv, acc[t], 0, 0, 0);
        }
    }
    float* outp = r1p + (size_t)kz * (NG * 1024);
#pragma unroll
    for (int t = 0; t < 2; ++t)
#pragma unroll
        for (int r = 0; r < 4; ++r)
            outp[(size_t)(mt * 16 + q * 4 + r) * 1024 + n0 + t * 16 + nlo] = acc[t][r];
}

// ---------------------------------------------------------------------------
// K5: fc2 partials, k_red1 folded into staging (r17). XCD-swizzled. 384 blocks.
// ---------------------------------------------------------------------------
__global__ __launch_bounds__(256) void k_fc2(
    const float* __restrict__ r1p, const float* __restrict__ w2,
    const float* __restrict__ b1, float* __restrict__ r2p)
{
    const int bid = blockIdx.x;                      // [0,384)
    const int cid = (bid & 7) * 48 + (bid >> 3);     // XCD-contiguous remap
    const int bx = cid % 3, by = (cid / 3) & 7, bz = cid / 24;
    const int m0 = bx * 64;
    const int n0 = by * 64;
    const int kb = bz * 64;
    __shared__ float rs[64][68];
    __shared__ float wss[64][68];
    const int tid = threadIdx.x;
    const int mt = tid & 15, nt = tid >> 4;
    float acc[4][4];
#pragma unroll
    for (int i = 0; i < 4; ++i)
#pragma unroll
        for (int j = 0; j < 4; ++j) acc[i][j] = 0.f;

    const size_t S = (size_t)NG * 1024;
    for (int idx = tid; idx < 1024; idx += 256) {
        const int r = idx >> 4, qq = idx & 15;
        const int gk = kb + qq * 4;
        // rs = h1 tile computed inline: relu(sum_kz r1p + b1)  (k_red1 order)
        const size_t hidx = (size_t)(m0 + r) * 1024 + gk;
        float4 s = *(const float4*)(r1p + hidx);
#pragma unroll
        for (int k = 1; k < 8; ++k) {
            const float4 t = *(const float4*)(r1p + (size_t)k * S + hidx);
            s.x += t.x; s.y += t.y; s.z += t.z; s.w += t.w;
        }
        const float4 bb = *(const float4*)(b1 + gk);
        float4 o;
        o.x = fmaxf(s.x + bb.x, 0.f);
        o.y = fmaxf(s.y + bb.y, 0.f);
        o.z = fmaxf(s.z + bb.z, 0.f);
        o.w = fmaxf(s.w + bb.w, 0.f);
        *(float4*)&rs[r][qq * 4] = o;
        *(float4*)&wss[r][qq * 4] = *(const float4*)(w2 + (size_t)(n0 + r) * 1024 + gk);
    }
    __syncthreads();
    for (int kq = 0; kq < 16; ++kq) {
        float4 av[4], bv[4];
#pragma unroll
        for (int i = 0; i < 4; ++i) av[i] = *(const float4*)&rs[mt + 16 * i][kq * 4];
#pragma unroll
        for (int j = 0; j < 4; ++j) bv[j] = *(const float4*)&wss[nt + 16 * j][kq * 4];
#pragma unroll
        for (int i = 0; i < 4; ++i)
#pragma unroll
            for (int j = 0; j < 4; ++j)
                acc[i][j] += av[i].x * bv[j].x + av[i].y * bv[j].y +
                             av[i].z * bv[j].z + av[i].w * bv[j].w;
    }
    float* outp = r2p + (size_t)bz * (NG * 512);
#pragma unroll
    for (int i = 0; i < 4; ++i)
#pragma unroll
        for (int j = 0; j < 4; ++j)
            outp[(size_t)(m0 + mt + 16 * i) * 512 + n0 + nt + 16 * j] = acc[i][j];
}

// K6: out = sum_kz r2p + fc2_b, 16 slices
__global__ __launch_bounds__(256) void k_red2(
    const float* __restrict__ r2p, const float* __restrict__ b2, float* __restrict__ out)
{
    const size_t i = ((size_t)blockIdx.x * 256 + threadIdx.x) * 4;
    const size_t S = (size_t)NG * 512;
    float4 s = *(const float4*)(r2p + i);
#pragma unroll
    for (int k = 1; k < 16; ++k) {
        const float4 t = *(const float4*)(r2p + (size_t)k * S + i);
        s.x += t.x; s.y += t.y; s.z += t.z; s.w += t.w;
    }
    const float4 bb = *(const float4*)(b2 + (i & 511));
    s.x += bb.x; s.y += bb.y; s.z += bb.z; s.w += bb.w;
    *(float4*)(out + i) = s;
}

// ---------------------------------------------------------------------------
extern "C" void kernel_launch(void* const* d_in, const int* in_sizes, int n_in,
                              void* d_out, int out_size, void* d_ws, size_t ws_size,
                              hipStream_t stream)
{
    const float* x0   = (const float*)d_in[0];
    const float* x1   = (const float*)d_in[1];
    const float* x2   = (const float*)d_in[2];
    const int*   ei0  = (const int*)d_in[3];
    const int*   ei1  = (const int*)d_in[4];
    const int*   ei2  = (const int*)d_in[5];
    const float* ea0  = (const float*)d_in[6];
    const float* ea1  = (const float*)d_in[7];
    const float* ea2  = (const float*)d_in[8];
    const float* gc1w = (const float*)d_in[9];
    const float* gc1b = (const float*)d_in[10];
    const float* gc4w = (const float*)d_in[11];
    const float* gc4b = (const float*)d_in[12];
    const float* fc1w = (const float*)d_in[13];
    const float* fc1b = (const float*)d_in[14];
    const float* fc2w = (const float*)d_in[15];
    const float* fc2b = (const float*)d_in[16];

    float*  ws  = (float*)d_ws;
    bf16_t* wbf = (bf16_t*)(ws + WB_OFF);
    bf16_t* fb  = (bf16_t*)(ws + FB_OFF);
    float*  r1p = ws + R1P_OFF;
    float*  r2p = ws + R2P_OFF;
    float*  out = (float*)d_out;

    k_main<<<NG + NCAST, CONVT, 0, stream>>>(x0, x1, x2, ei0, ei1, ei2,
                                             ea0, ea1, ea2, fc1w, gc1w,
                                             gc1b, gc4w, gc4b, wbf, fb);
    k_fc1 <<<768, 256, 0, stream>>>(fb, wbf, r1p);
    k_fc2 <<<384, 256, 0, stream>>>(r1p, fc2w, fc1b, r2p);
    k_red2<<<96, 256, 0, stream>>>(r2p, fc2b, out);
}